// Round 11
// baseline (242.055 us; speedup 1.0000x reference)
//
#include <hip/hip_runtime.h>
#include <hip/hip_bf16.h>
#include <math.h>
#include <stdint.h>

// Problem constants (fixed by the reference)
#define B_SZ 2
#define T_SZ 1024
#define S_SZ 1024
#define NQ 16
#define NKV 4
#define HD 128
#define DQ 2048
#define DKV 2048
#define DOUT 2048

typedef _Float16 half8 __attribute__((ext_vector_type(8)));
typedef _Float16 half4 __attribute__((ext_vector_type(4)));
typedef float f32x4 __attribute__((ext_vector_type(4)));

__device__ __forceinline__ half8 load8_f16(const _Float16* p) {
    return *reinterpret_cast<const half8*>(p);
}

// ---- async global->LDS, 16 B per lane; lds base must be wave-uniform ------
__device__ __forceinline__ void stage16(const _Float16* g, _Float16* l, int lane) {
#if __has_builtin(__builtin_amdgcn_global_load_lds)
    __builtin_amdgcn_global_load_lds(
        (const __attribute__((address_space(1))) uint32_t*)g,
        (__attribute__((address_space(3))) uint32_t*)l, 16, 0, 0);
#else
    *reinterpret_cast<half8*>(l + lane * 8) = *reinterpret_cast<const half8*>(g);
#endif
}

// ---- DPP 16-lane butterfly reduce (masks {1,2,7,15}). VALU-only. ----------
#define DPPF(x, ctrl) __int_as_float(__builtin_amdgcn_mov_dpp(__float_as_int(x), ctrl, 0xF, 0xF, true))
__device__ __forceinline__ float max16(float x) {
    x = fmaxf(x, DPPF(x, 0xB1));    // quad_perm [1,0,3,2]  : xor 1
    x = fmaxf(x, DPPF(x, 0x4E));    // quad_perm [2,3,0,1]  : xor 2
    x = fmaxf(x, DPPF(x, 0x141));   // row_half_mirror      : xor 7
    x = fmaxf(x, DPPF(x, 0x140));   // row_mirror           : xor 15
    return x;
}
__device__ __forceinline__ float sum16(float x) {
    x += DPPF(x, 0xB1);
    x += DPPF(x, 0x4E);
    x += DPPF(x, 0x141);
    x += DPPF(x, 0x140);
    return x;
}

// ---------------------------------------------------------------------------
// device helpers for fused prep kernels (block-uniform routing)
// ---------------------------------------------------------------------------
__device__ __forceinline__ void tr_blk(const float* __restrict__ in,
                                       _Float16* __restrict__ out,
                                       int R, int C, int bx, int by,
                                       _Float16 (*tile)[72]) {
    const int tx = threadIdx.x & 15, ty = threadIdx.x >> 4;
    const int r0 = by * 64, c0 = bx * 64;
    #pragma unroll
    for (int i = 0; i < 4; ++i) {
        int r = ty + i * 16;
        float4 v = *reinterpret_cast<const float4*>(&in[(size_t)(r0 + r) * C + c0 + tx * 4]);
        tile[r][tx * 4 + 0] = (_Float16)v.x;
        tile[r][tx * 4 + 1] = (_Float16)v.y;
        tile[r][tx * 4 + 2] = (_Float16)v.z;
        tile[r][tx * 4 + 3] = (_Float16)v.w;
    }
    __syncthreads();
    #pragma unroll
    for (int i = 0; i < 4; ++i) {
        int oc = ty + i * 16;
        half4 v;
        v[0] = tile[tx * 4 + 0][oc];
        v[1] = tile[tx * 4 + 1][oc];
        v[2] = tile[tx * 4 + 2][oc];
        v[3] = tile[tx * 4 + 3][oc];
        *reinterpret_cast<half4*>(&out[(size_t)(c0 + oc) * R + r0 + tx * 4]) = v;
    }
}

// fp16 -> fp16 transpose of a 64x64 tile: out[c][r] = in[r][c]
__device__ __forceinline__ void tr16_blk(const _Float16* __restrict__ in,
                                         _Float16* __restrict__ out,
                                         int Cin, int Cout, int r0, int c0,
                                         _Float16 (*tile)[72]) {
    const int tx = threadIdx.x & 15, ty = threadIdx.x >> 4;
    #pragma unroll
    for (int i = 0; i < 4; ++i) {
        int r = ty + i * 16;
        half4 v = *reinterpret_cast<const half4*>(&in[(size_t)(r0 + r) * Cin + c0 + tx * 4]);
        tile[r][tx * 4 + 0] = v[0];
        tile[r][tx * 4 + 1] = v[1];
        tile[r][tx * 4 + 2] = v[2];
        tile[r][tx * 4 + 3] = v[3];
    }
    __syncthreads();
    #pragma unroll
    for (int i = 0; i < 4; ++i) {
        int oc = ty + i * 16;
        half4 v;
        v[0] = tile[tx * 4 + 0][oc];
        v[1] = tile[tx * 4 + 1][oc];
        v[2] = tile[tx * 4 + 2][oc];
        v[3] = tile[tx * 4 + 3][oc];
        *reinterpret_cast<half4*>(&out[(size_t)(c0 + oc) * Cout + r0 + tx * 4]) = v;
    }
}

// Vectorized RoPE: thread = (row bl, 4-h group hq, head slot ns); handles
// NHEADS/NSLOT heads, reusing trig. exp2f timescale + fast __sinf/__cosf.
template <int NHEADS, int NSLOT, int RS>
__device__ __forceinline__ void rope_fast(_Float16* __restrict__ x,
                                          const int* __restrict__ pos, int vb) {
    const int t = vb * 256 + (int)threadIdx.x;
    const int hq = t & 15;
    const int ns = (t >> 4) % NSLOT;
    const int bl = (t >> 4) / NSLOT;
    const float p = (float)pos[bl];
    const float C = -0.2076205059304601f;   // -log2(10000)/64
    float s[4], c[4];
    #pragma unroll
    for (int j = 0; j < 4; ++j) {
        float ang = p * exp2f((float)(hq * 4 + j) * C);
        s[j] = __sinf(ang);
        c[j] = __cosf(ang);
    }
    #pragma unroll
    for (int i = 0; i < NHEADS / NSLOT; ++i) {
        const int n = ns + i * NSLOT;
        size_t base = (size_t)bl * RS + (size_t)n * HD + hq * 4;
        half4 a  = *reinterpret_cast<half4*>(&x[base]);
        half4 b2 = *reinterpret_cast<half4*>(&x[base + 64]);
        half4 o1, o2;
        #pragma unroll
        for (int j = 0; j < 4; ++j) {
            float x1 = (float)a[j], x2 = (float)b2[j];
            o1[j] = (_Float16)(x1 * c[j] - x2 * s[j]);
            o2[j] = (_Float16)(x2 * c[j] + x1 * s[j]);
        }
        *reinterpret_cast<half4*>(&x[base])      = o1;
        *reinterpret_cast<half4*>(&x[base + 64]) = o2;
    }
}

// prep1: transpose Wq, Wk, Wv only (conversion of Xq/Xkv is now fused into
// the projection GEMM's A-staging).  1536 blocks.
__global__ __launch_bounds__(256) void prep1(const float* __restrict__ Wq, _Float16* __restrict__ WqT,
                                             const float* __restrict__ Wk, const float* __restrict__ Wv,
                                             _Float16* __restrict__ WkvT) {
    __shared__ _Float16 tile[64][72];
    int bx = blockIdx.x;
    if (bx < 1024) { tr_blk(Wq, WqT, 2048, 2048, bx & 31, bx >> 5, tile); return; }
    bx -= 1024;
    if (bx < 256) { tr_blk(Wk, WkvT, 2048, 512, bx & 7, bx >> 3, tile); return; }
    bx -= 256;
    tr_blk(Wv, WkvT + (size_t)512 * 2048, 2048, 512, bx & 7, bx >> 3, tile);
}

// prep2: transpose Wo; RoPE on Q and KV (vectorized); V^T.  2048 blocks.
// VTh layout: [(b*NKV+kn)][h(128)][s(1024)] fp16 (V^T per kv-head).
__global__ __launch_bounds__(256) void prep2(const float* __restrict__ Wo, _Float16* __restrict__ WoT,
                                             _Float16* __restrict__ Qh, const int* __restrict__ qpos,
                                             _Float16* __restrict__ KVh, const int* __restrict__ kpos,
                                             _Float16* __restrict__ VTh) {
    __shared__ _Float16 tile[64][72];
    int bx = blockIdx.x;
    if (bx < 1024) { tr_blk(Wo, WoT, 2048, 2048, bx & 31, bx >> 5, tile); return; }
    bx -= 1024;
    if (bx < 512) { rope_fast<NQ, 4, NQ * HD>(Qh, qpos, bx); return; }
    bx -= 512;
    if (bx < 256) { rope_fast<NKV, 2, 1024>(KVh, kpos, bx); return; }
    bx -= 256;
    // V transpose: 256 blocks = 8 heads x 32 tiles (16 s-tiles x 2 h-tiles)
    {
        const int head = bx >> 5;            // b*4 + kn
        const int t = bx & 31;
        const int sx = t & 15, hx = t >> 4;
        const int b = head >> 2, kn = head & 3;
        const _Float16* in = KVh + (size_t)(b * S_SZ) * 1024 + 512 + kn * HD;
        _Float16* out = VTh + (size_t)head * HD * S_SZ;
        tr16_blk(in, out, 1024, 1024, sx * 64, hx * 64, tile);
    }
}

// ---------------------------------------------------------------------------
// GEMM tile body (fp16 A): C[bm:+BM][bn:+BN] = A * Bt^T over [kbeg,kend).
// Coalesced swizzled async staging + 2-phase double-buffer (round-2 notes).
// ---------------------------------------------------------------------------
template <int BM, int BN, typename TC>
__device__ __forceinline__ void gemm_tile(const _Float16* __restrict__ A,
                                          const _Float16* __restrict__ Bt,
                                          TC* __restrict__ C,
                                          int N, int K, int kbeg, int kend,
                                          int bm, int bn, _Float16* lds) {
    constexpr int ASEG = BM / 8, BSEG = BN / 8, TSEG = ASEG + BSEG, PSEG = TSEG / 4;
    constexpr int BUFSZ = TSEG * 512;           // fp16 elems per LDS buffer
    const int tid = threadIdx.x, lane = tid & 63, w = tid >> 6;
    const int quad = lane >> 4, l16 = lane & 15;
    constexpr int WM = BM / 2, WN = BN / 2, MI = WM / 16, NI = WN / 16;
    const int wm = (w >> 1) * WM, wn = (w & 1) * WN;

    // staging lane geometry: 8 rows x 8 swizzled 16B k-chunks per segment
    const int srl = lane >> 3;              // row within the 8-row stripe
    const int skb = (lane & 7) ^ srl;       // pre-swizzled global k-chunk

    const _Float16* gp[PSEG];
    _Float16* lp[PSEG];
    #pragma unroll
    for (int p = 0; p < PSEG; ++p) {
        int s = w + p * 4;
        if (s < ASEG) {
            gp[p] = A + (size_t)(bm + s * 8 + srl) * K + kbeg + skb * 8;
        } else {
            gp[p] = Bt + (size_t)(bn + (s - ASEG) * 8 + srl) * K + kbeg + skb * 8;
        }
        lp[p] = lds + s * 512;
    }

    f32x4 acc[MI][NI];
    #pragma unroll
    for (int i = 0; i < MI; ++i)
        #pragma unroll
        for (int j = 0; j < NI; ++j)
            acc[i][j] = (f32x4){0.f, 0.f, 0.f, 0.f};

    const int nsteps = (kend - kbeg) >> 6;

    // prologue: stage k-step 0 into buffer 0
    #pragma unroll
    for (int p = 0; p < PSEG; ++p)
        stage16(gp[p], lp[p], lane);
    __syncthreads();                         // vmcnt(0) drain + barrier

    const int rxa = l16 & 7;                 // row&7 for fragment swizzle
    int cur = 0;
    for (int it = 0; it < nsteps; ++it) {
        // issue prefetch of k-step it+1 into the other buffer FIRST
        if (it + 1 < nsteps) {
            const int ko = (it + 1) * 64;
            const int nb = (cur ^ 1) * BUFSZ;
            #pragma unroll
            for (int p = 0; p < PSEG; ++p)
                stage16(gp[p] + ko, lp[p] + nb, lane);
        }
        const _Float16* lb = lds + cur * BUFSZ;
        #pragma unroll
        for (int h = 0; h < 2; ++h) {        // two 32-k MFMA steps per round
            const int kb0 = h * 4 + quad;    // k-chunk this lane needs
            const int kswz = (kb0 ^ rxa) * 8;
            half8 af[MI], bf[NI];
            #pragma unroll
            for (int i = 0; i < MI; ++i) {
                const int r = wm + 16 * i + l16;
                af[i] = *reinterpret_cast<const half8*>(&lb[r * 64 + kswz]);
            }
            #pragma unroll
            for (int j = 0; j < NI; ++j) {
                const int r = wn + 16 * j + l16;
                bf[j] = *reinterpret_cast<const half8*>(&lb[BM * 64 + r * 64 + kswz]);
            }
            #pragma unroll
            for (int i = 0; i < MI; ++i)
                #pragma unroll
                for (int j = 0; j < NI; ++j)
                    acc[i][j] = __builtin_amdgcn_mfma_f32_16x16x32_f16(af[i], bf[j], acc[i][j], 0, 0, 0);
        }
        __syncthreads();   // drains prefetch vmcnt(0); all reads of cur done
        cur ^= 1;
    }

    #pragma unroll
    for (int i = 0; i < MI; ++i)
        #pragma unroll
        for (int j = 0; j < NI; ++j)
            #pragma unroll
            for (int r = 0; r < 4; ++r) {
                size_t idx = (size_t)(bm + wm + 16 * i + quad * 4 + r) * N + bn + wn + 16 * j + l16;
                C[idx] = (TC)acc[i][j][r];
            }
}

// ---------------------------------------------------------------------------
// GEMM tile body (fp32 A, in-flight convert): A is read directly as fp32
// (8 rows x 256 B coalesced per wave instr), converted to fp16 in registers,
// and ds_write'n into the SAME swizzled LDS layout gemm_tile uses. B keeps
// the async global_load_lds path. T14 split: A loads issue BEFORE the MFMA
// block; cvt+ds_write after (load latency hides under compute).
// Eliminates the separate fp32->fp16 conversion pass over Xq/Xkv.
// ---------------------------------------------------------------------------
template <int BM, int BN>
__device__ __forceinline__ void gemm_tile_a32(const float* __restrict__ A,
                                              const _Float16* __restrict__ Bt,
                                              _Float16* __restrict__ C,
                                              int N, int K,
                                              int bm, int bn, _Float16* lds) {
    constexpr int ASEG = BM / 8, BSEG = BN / 8, TSEG = ASEG + BSEG;
    constexpr int PA = ASEG / 4, PB = BSEG / 4;
    constexpr int BUFSZ = TSEG * 512;           // fp16 elems per LDS buffer
    const int tid = threadIdx.x, lane = tid & 63, w = tid >> 6;
    const int quad = lane >> 4, l16 = lane & 15;
    constexpr int WM = BM / 2, WN = BN / 2, MI = WM / 16, NI = WN / 16;
    const int wm = (w >> 1) * WM, wn = (w & 1) * WN;

    const int srl = lane >> 3;              // row within the 8-row stripe
    const int skb = (lane & 7) ^ srl;       // pre-swizzled global k-chunk

    const float* ga[PA];
    _Float16* la[PA];                       // per-lane LDS dest (reg-staged)
    #pragma unroll
    for (int p = 0; p < PA; ++p) {
        int s = w + p * 4;
        ga[p] = A + (size_t)(bm + s * 8 + srl) * K + skb * 8;
        la[p] = lds + s * 512 + lane * 8;
    }
    const _Float16* gb[PB];
    _Float16* lb_[PB];                      // wave-uniform LDS base (async)
    #pragma unroll
    for (int p = 0; p < PB; ++p) {
        int s = ASEG + w + p * 4;
        gb[p] = Bt + (size_t)(bn + (s - ASEG) * 8 + srl) * K + skb * 8;
        lb_[p] = lds + s * 512;
    }

    f32x4 acc[MI][NI];
    #pragma unroll
    for (int i = 0; i < MI; ++i)
        #pragma unroll
        for (int j = 0; j < NI; ++j)
            acc[i][j] = (f32x4){0.f, 0.f, 0.f, 0.f};

    const int nsteps = K >> 6;

    // prologue: stage k-step 0 into buffer 0
    {
        float4 av[PA][2];
        #pragma unroll
        for (int p = 0; p < PA; ++p) {
            av[p][0] = *reinterpret_cast<const float4*>(ga[p]);
            av[p][1] = *reinterpret_cast<const float4*>(ga[p] + 4);
        }
        #pragma unroll
        for (int p = 0; p < PB; ++p)
            stage16(gb[p], lb_[p], lane);
        #pragma unroll
        for (int p = 0; p < PA; ++p) {
            half8 h;
            h[0] = (_Float16)av[p][0].x; h[1] = (_Float16)av[p][0].y;
            h[2] = (_Float16)av[p][0].z; h[3] = (_Float16)av[p][0].w;
            h[4] = (_Float16)av[p][1].x; h[5] = (_Float16)av[p][1].y;
            h[6] = (_Float16)av[p][1].z; h[7] = (_Float16)av[p][1].w;
            *reinterpret_cast<half8*>(la[p]) = h;
        }
    }
    __syncthreads();                         // vmcnt + lgkmcnt drain

    const int rxa = l16 & 7;                 // row&7 for fragment swizzle
    int cur = 0;
    for (int it = 0; it < nsteps; ++it) {
        const bool pf = (it + 1 < nsteps);
        const int ko = (it + 1) * 64;
        const int nb = (cur ^ 1) * BUFSZ;
        // issue A loads (regs) and B async stage for k-step it+1 FIRST
        float4 av[PA][2];
        if (pf) {
            #pragma unroll
            for (int p = 0; p < PA; ++p) {
                av[p][0] = *reinterpret_cast<const float4*>(ga[p] + ko);
                av[p][1] = *reinterpret_cast<const float4*>(ga[p] + ko + 4);
            }
            #pragma unroll
            for (int p = 0; p < PB; ++p)
                stage16(gb[p] + ko, lb_[p] + nb, lane);
        }
        const _Float16* lb = lds + cur * BUFSZ;
        #pragma unroll
        for (int h = 0; h < 2; ++h) {        // two 32-k MFMA steps per round
            const int kb0 = h * 4 + quad;
            const int kswz = (kb0 ^ rxa) * 8;
            half8 af[MI], bf[NI];
            #pragma unroll
            for (int i = 0; i < MI; ++i) {
                const int r = wm + 16 * i + l16;
                af[i] = *reinterpret_cast<const half8*>(&lb[r * 64 + kswz]);
            }
            #pragma unroll
            for (int j = 0; j < NI; ++j) {
                const int r = wn + 16 * j + l16;
                bf[j] = *reinterpret_cast<const half8*>(&lb[BM * 64 + r * 64 + kswz]);
            }
            #pragma unroll
            for (int i = 0; i < MI; ++i)
                #pragma unroll
                for (int j = 0; j < NI; ++j)
                    acc[i][j] = __builtin_amdgcn_mfma_f32_16x16x32_f16(af[i], bf[j], acc[i][j], 0, 0, 0);
        }
        // cvt + write A regs into the next buffer (after MFMA: latency hidden)
        if (pf) {
            #pragma unroll
            for (int p = 0; p < PA; ++p) {
                half8 h;
                h[0] = (_Float16)av[p][0].x; h[1] = (_Float16)av[p][0].y;
                h[2] = (_Float16)av[p][0].z; h[3] = (_Float16)av[p][0].w;
                h[4] = (_Float16)av[p][1].x; h[5] = (_Float16)av[p][1].y;
                h[6] = (_Float16)av[p][1].z; h[7] = (_Float16)av[p][1].w;
                *reinterpret_cast<half8*>(la[p] + nb) = h;
            }
        }
        __syncthreads();   // drains B vmcnt + A ds_writes; reads of cur done
        cur ^= 1;
    }

    #pragma unroll
    for (int i = 0; i < MI; ++i)
        #pragma unroll
        for (int j = 0; j < NI; ++j)
            #pragma unroll
            for (int r = 0; r < 4; ++r) {
                size_t idx = (size_t)(bm + wm + 16 * i + quad * 4 + r) * N + bn + wn + 16 * j + l16;
                C[idx] = (_Float16)acc[i][j][r];
            }
}

// Fused Q-proj + KV-proj reading fp32 X directly:
// blocks [0,512) -> Q (N=2048); [512,768) -> KV (N=1024).
__global__ __launch_bounds__(256) void proj_fused(const float* __restrict__ Xq,
                                                  const _Float16* __restrict__ WqT,
                                                  _Float16* __restrict__ Qh,
                                                  const float* __restrict__ Xkv,
                                                  const _Float16* __restrict__ WkvT,
                                                  _Float16* __restrict__ KVh) {
    __shared__ __align__(16) _Float16 lds[2 * (128 + 64) * 64];
    int bx = blockIdx.x;
    if (bx < 512) {
        gemm_tile_a32<128, 64>(Xq, WqT, Qh, 2048, 2048,
                               (bx & 15) * 128, (bx >> 4) * 64, lds);
    } else {
        bx -= 512;
        gemm_tile_a32<128, 64>(Xkv, WkvT, KVh, 1024, 2048,
                               (bx & 15) * 128, (bx >> 4) * 64, lds);
    }
}

// Out-proj: full K=2048, direct fp32 store (no atomics, no memset). 512 blocks.
__global__ __launch_bounds__(256) void gemm_out(const _Float16* __restrict__ A,
                                                const _Float16* __restrict__ Bt,
                                                float* __restrict__ C) {
    __shared__ __align__(16) _Float16 lds[2 * (128 + 64) * 64];
    const int bx = blockIdx.x;
    gemm_tile<128, 64, float>(A, Bt, C, 2048, 2048, 0, 2048,
                              (bx & 15) * 128, (bx >> 4) * 64, lds);
}

// ---------------------------------------------------------------------------
// Flash attention (round-10 known-best: async dbuf staging + XCD remap +
// defer-max THR=8 + DPP reductions). FROZEN this round.
// ---------------------------------------------------------------------------
__global__ __launch_bounds__(256) void attn_kernel(const _Float16* __restrict__ Q,
                                                   const _Float16* __restrict__ KV,
                                                   const _Float16* __restrict__ VT,
                                                   _Float16* __restrict__ O) {
    constexpr int KBUF = 64 * 128;            // fp16 per K buffer
    constexpr int VBUF = 128 * 64;            // fp16 per Vt buffer
    constexpr int BUFSZ = KBUF + VBUF;        // 16384 fp16 = 32 KB
    __shared__ __align__(16) _Float16 lds[2 * BUFSZ];       // 64 KB
    __shared__ __align__(16) _Float16 Ps[4][16][72];        // 9 KB
    const int tid = threadIdx.x, lane = tid & 63, w = tid >> 6;
    const int quad = lane >> 4, l16 = lane & 15;
    const int hw = blockIdx.x;
    const int blk = (hw & 7) * 64 + (hw >> 3);   // XCD-aligned logical id
    const int t0 = (blk & 15) * 64;
    const int n  = (blk >> 4) & 15;
    const int b  = blk >> 8;
    const int kn = n >> 2;
    const _Float16* KVb  = KV + (size_t)b * S_SZ * 1024 + kn * HD;
    const _Float16* Vhead = VT + (size_t)(b * NKV + kn) * HD * S_SZ;

    // staging lane geometry (wave-uniform LDS bases; per-lane global addrs)
    const int krow_i = lane >> 4;             // row-in-seg for K (4 rows/seg)
    const int kcp    = lane & 15;             // chunk pos for K
    const int vrow_i = lane >> 3;             // row-in-seg for Vt (8 rows/seg)
    const int vcp    = lane & 7;              // chunk pos for Vt

    half8 qf[4];
    #pragma unroll
    for (int kh = 0; kh < 4; ++kh)
        qf[kh] = load8_f16(&Q[(((size_t)b * T_SZ + t0 + w * 16 + l16) * NQ + n) * HD + kh * 32 + quad * 8]);

    f32x4 o_acc[8];
    #pragma unroll
    for (int i = 0; i < 8; ++i) o_acc[i] = (f32x4){0.f, 0.f, 0.f, 0.f};
    float m_row[4] = {-1e30f, -1e30f, -1e30f, -1e30f};
    float l_part[4] = {0.f, 0.f, 0.f, 0.f};

    // ---- stage one s-tile (64 kv rows) into buffer `buf` -----------------
    auto stage_tile = [&](int s0, int buf) {
        _Float16* kb = lds + buf * BUFSZ;
        _Float16* vb = kb + KBUF;
        #pragma unroll
        for (int j = 0; j < 4; ++j) {
            const int s = w + j * 4;               // segment 0..15
            const int row = 4 * s + krow_i;        // K row 0..63
            const int kc = kcp ^ (row & 7);        // pre-swizzled chunk
            stage16(KVb + (size_t)(s0 + row) * 1024 + kc * 8, kb + s * 512, lane);
        }
        #pragma unroll
        for (int j = 0; j < 4; ++j) {
            const int s = w + j * 4;
            const int row = 8 * s + vrow_i;        // Vt row (h) 0..127
            const int vc = vcp ^ (row & 7);
            stage16(Vhead + (size_t)row * S_SZ + s0 + vc * 8, vb + s * 512, lane);
        }
    };

    stage_tile(0, 0);
    __syncthreads();

    const int rx = l16 & 7;                        // row&7 for all reads
    int cur = 0;
    for (int t = 0; t < S_SZ / 64; ++t) {
        if (t + 1 < S_SZ / 64)
            stage_tile((t + 1) * 64, cur ^ 1);
        const _Float16* Kb = lds + cur * BUFSZ;
        const _Float16* Vb = Kb + KBUF;

        f32x4 sf[4];
        __builtin_amdgcn_s_setprio(1);
        #pragma unroll
        for (int i4 = 0; i4 < 4; ++i4) {
            const int srow = i4 * 16 + l16;        // K row 0..63
            f32x4 sa = (f32x4){0.f, 0.f, 0.f, 0.f};
            #pragma unroll
            for (int kh = 0; kh < 4; ++kh) {
                const int c = kh * 4 + quad;       // chunk 0..15
                half8 bk = *reinterpret_cast<const half8*>(
                    &Kb[srow * 128 + ((c ^ rx) * 8)]);
                sa = __builtin_amdgcn_mfma_f32_16x16x32_f16(qf[kh], bk, sa, 0, 0, 0);
            }
            sf[i4] = sa;
        }
        __builtin_amdgcn_s_setprio(0);

        float mc[4];
        #pragma unroll
        for (int r = 0; r < 4; ++r)
            mc[r] = max16(fmaxf(fmaxf(sf[0][r], sf[1][r]), fmaxf(sf[2][r], sf[3][r])));
        // defer-max: rescale only when a row max grows by more than THR=8.
        bool grow = (mc[0] > m_row[0] + 8.f) | (mc[1] > m_row[1] + 8.f) |
                    (mc[2] > m_row[2] + 8.f) | (mc[3] > m_row[3] + 8.f);
        if (__any(grow)) {
            #pragma unroll
            for (int r = 0; r < 4; ++r) {
                float mn = fmaxf(m_row[r], mc[r]);
                float alpha = __expf(m_row[r] - mn);
                m_row[r] = mn;
                l_part[r] *= alpha;
                #pragma unroll
                for (int ht = 0; ht < 8; ++ht)
                    o_acc[ht][r] *= alpha;
            }
        }
        #pragma unroll
        for (int r = 0; r < 4; ++r) {
            float p0 = __expf(sf[0][r] - m_row[r]);
            float p1 = __expf(sf[1][r] - m_row[r]);
            float p2 = __expf(sf[2][r] - m_row[r]);
            float p3 = __expf(sf[3][r] - m_row[r]);
            l_part[r] += (p0 + p1) + (p2 + p3);
            Ps[w][quad * 4 + r][l16]      = (_Float16)p0;
            Ps[w][quad * 4 + r][16 + l16] = (_Float16)p1;
            Ps[w][quad * 4 + r][32 + l16] = (_Float16)p2;
            Ps[w][quad * 4 + r][48 + l16] = (_Float16)p3;
        }
        __builtin_amdgcn_wave_barrier();
        half8 ap0 = *reinterpret_cast<const half8*>(&Ps[w][l16][quad * 8]);
        half8 ap1 = *reinterpret_cast<const half8*>(&Ps[w][l16][32 + quad * 8]);
        __builtin_amdgcn_wave_barrier();
        __builtin_amdgcn_s_setprio(1);
        #pragma unroll
        for (int ht = 0; ht < 8; ++ht) {
            const int vrow = ht * 16 + l16;        // h row 0..127
            half8 bv0 = *reinterpret_cast<const half8*>(
                &Vb[vrow * 64 + ((quad ^ rx) * 8)]);
            o_acc[ht] = __builtin_amdgcn_mfma_f32_16x16x32_f16(ap0, bv0, o_acc[ht], 0, 0, 0);
            half8 bv1 = *reinterpret_cast<const half8*>(
                &Vb[vrow * 64 + (((4 + quad) ^ rx) * 8)]);
            o_acc[ht] = __builtin_amdgcn_mfma_f32_16x16x32_f16(ap1, bv1, o_acc[ht], 0, 0, 0);
        }
        __builtin_amdgcn_s_setprio(0);

        __syncthreads();     // drains prefetch vmcnt(0); all reads of cur done
        cur ^= 1;
    }

    float inv_l[4];
    #pragma unroll
    for (int r = 0; r < 4; ++r)
        inv_l[r] = 1.f / fmaxf(sum16(l_part[r]), 1e-30f);
    #pragma unroll
    for (int ht = 0; ht < 8; ++ht)
        #pragma unroll
        for (int r = 0; r < 4; ++r)
            O[(((size_t)b * T_SZ + t0 + w * 16 + quad * 4 + r) * NQ + n) * HD + ht * 16 + l16] =
                (_Float16)(o_acc[ht][r] * inv_l[r]);
}

// ---------------------------------------------------------------------------
extern "C" void kernel_launch(void* const* d_in, const int* in_sizes, int n_in,
                              void* d_out, int out_size, void* d_ws, size_t ws_size,
                              hipStream_t stream) {
    const float* Xq   = (const float*)d_in[0];
    const float* Xkv  = (const float*)d_in[1];
    const int*   qpos = (const int*)d_in[2];
    const int*   kpos = (const int*)d_in[3];
    const float* Wq   = (const float*)d_in[4];
    const float* Wk   = (const float*)d_in[5];
    const float* Wv   = (const float*)d_in[6];
    const float* Wo   = (const float*)d_in[7];
    float* out = (float*)d_out;

    // workspace packing with lifetime reuse
    const size_t SZ8 = 8388608;
    uint8_t* ws = (uint8_t*)d_ws;
    _Float16* WqT   = (_Float16*)(ws + 2 * SZ8);
    _Float16* WkvT  = (_Float16*)(ws + 3 * SZ8);
    _Float16* Qh    = (_Float16*)(ws + 3 * SZ8 + 4194304);
    _Float16* Ah  = (_Float16*)(ws);          // slot 0 (free until attn)
    _Float16* WoT = (_Float16*)(ws + SZ8);    // slot 1 (free until prep2)
    _Float16* KVh = WqT;    // KV reuses WqT (dead after proj)
    _Float16* VTh = WkvT;   // V^T reuses WkvT (dead after proj), 2 MB of 4 MB

    dim3 blk(256);
    // prep1: Wq/Wk/Wv transposes only (conversion fused into proj)
    prep1<<<1536, blk, 0, stream>>>(Wq, WqT, Wk, Wv, WkvT);
    // fused Q + KV projection reading fp32 X directly (768 blocks)
    proj_fused<<<768, blk, 0, stream>>>(Xq, WqT, Qh, Xkv, WkvT, KVh);
    // prep2: Wo transpose + vectorized RoPE + V^T (2048 blocks)
    prep2<<<2048, blk, 0, stream>>>(Wo, WoT, Qh, qpos, KVh, kpos, VTh);
    // GQA flash attention (512 blocks x 256 thr, XCD-aligned, async dbuf)
    attn_kernel<<<512, blk, 0, stream>>>(Qh, KVh, VTh, Ah);
    // output projection: full-K, direct fp32 store (512 blocks)
    gemm_out<<<512, blk, 0, stream>>>(Ah, WoT, out);
}

// Round 13
// 216.241 us; speedup vs baseline: 1.1194x; 1.1194x over previous
//
#include <hip/hip_runtime.h>
#include <hip/hip_bf16.h>
#include <math.h>
#include <stdint.h>

// Problem constants (fixed by the reference)
#define B_SZ 2
#define T_SZ 1024
#define S_SZ 1024
#define NQ 16
#define NKV 4
#define HD 128
#define DQ 2048
#define DKV 2048
#define DOUT 2048

typedef _Float16 half8 __attribute__((ext_vector_type(8)));
typedef _Float16 half4 __attribute__((ext_vector_type(4)));
typedef float f32x4 __attribute__((ext_vector_type(4)));

__device__ __forceinline__ half8 load8_f16(const _Float16* p) {
    return *reinterpret_cast<const half8*>(p);
}

// ---- async global->LDS, 16 B per lane; lds base must be wave-uniform ------
__device__ __forceinline__ void stage16(const _Float16* g, _Float16* l, int lane) {
#if __has_builtin(__builtin_amdgcn_global_load_lds)
    __builtin_amdgcn_global_load_lds(
        (const __attribute__((address_space(1))) uint32_t*)g,
        (__attribute__((address_space(3))) uint32_t*)l, 16, 0, 0);
#else
    *reinterpret_cast<half8*>(l + lane * 8) = *reinterpret_cast<const half8*>(g);
#endif
}

// ---- DPP 16-lane butterfly reduce (masks {1,2,7,15}). VALU-only. ----------
#define DPPF(x, ctrl) __int_as_float(__builtin_amdgcn_mov_dpp(__float_as_int(x), ctrl, 0xF, 0xF, true))
__device__ __forceinline__ float max16(float x) {
    x = fmaxf(x, DPPF(x, 0xB1));    // quad_perm [1,0,3,2]  : xor 1
    x = fmaxf(x, DPPF(x, 0x4E));    // quad_perm [2,3,0,1]  : xor 2
    x = fmaxf(x, DPPF(x, 0x141));   // row_half_mirror      : xor 7
    x = fmaxf(x, DPPF(x, 0x140));   // row_mirror           : xor 15
    return x;
}
__device__ __forceinline__ float sum16(float x) {
    x += DPPF(x, 0xB1);
    x += DPPF(x, 0x4E);
    x += DPPF(x, 0x141);
    x += DPPF(x, 0x140);
    return x;
}

// ---------------------------------------------------------------------------
// device helpers for fused prep kernels (block-uniform routing)
// ---------------------------------------------------------------------------
__device__ __forceinline__ void conv_blk(const float* __restrict__ in,
                                         _Float16* __restrict__ out, int vb) {
    size_t i = ((size_t)vb * 256 + threadIdx.x) * 8;
    float4 a = *reinterpret_cast<const float4*>(in + i);
    float4 b = *reinterpret_cast<const float4*>(in + i + 4);
    half8 r;
    r[0] = (_Float16)a.x; r[1] = (_Float16)a.y; r[2] = (_Float16)a.z; r[3] = (_Float16)a.w;
    r[4] = (_Float16)b.x; r[5] = (_Float16)b.y; r[6] = (_Float16)b.z; r[7] = (_Float16)b.w;
    *reinterpret_cast<half8*>(out + i) = r;
}

__device__ __forceinline__ void tr_blk(const float* __restrict__ in,
                                       _Float16* __restrict__ out,
                                       int R, int C, int bx, int by,
                                       _Float16 (*tile)[72]) {
    const int tx = threadIdx.x & 15, ty = threadIdx.x >> 4;
    const int r0 = by * 64, c0 = bx * 64;
    #pragma unroll
    for (int i = 0; i < 4; ++i) {
        int r = ty + i * 16;
        float4 v = *reinterpret_cast<const float4*>(&in[(size_t)(r0 + r) * C + c0 + tx * 4]);
        tile[r][tx * 4 + 0] = (_Float16)v.x;
        tile[r][tx * 4 + 1] = (_Float16)v.y;
        tile[r][tx * 4 + 2] = (_Float16)v.z;
        tile[r][tx * 4 + 3] = (_Float16)v.w;
    }
    __syncthreads();
    #pragma unroll
    for (int i = 0; i < 4; ++i) {
        int oc = ty + i * 16;
        half4 v;
        v[0] = tile[tx * 4 + 0][oc];
        v[1] = tile[tx * 4 + 1][oc];
        v[2] = tile[tx * 4 + 2][oc];
        v[3] = tile[tx * 4 + 3][oc];
        *reinterpret_cast<half4*>(&out[(size_t)(c0 + oc) * R + r0 + tx * 4]) = v;
    }
}

// fp16 -> fp16 transpose of a 64x64 tile: out[c][r] = in[r][c]
__device__ __forceinline__ void tr16_blk(const _Float16* __restrict__ in,
                                         _Float16* __restrict__ out,
                                         int Cin, int Cout, int r0, int c0,
                                         _Float16 (*tile)[72]) {
    const int tx = threadIdx.x & 15, ty = threadIdx.x >> 4;
    #pragma unroll
    for (int i = 0; i < 4; ++i) {
        int r = ty + i * 16;
        half4 v = *reinterpret_cast<const half4*>(&in[(size_t)(r0 + r) * Cin + c0 + tx * 4]);
        tile[r][tx * 4 + 0] = v[0];
        tile[r][tx * 4 + 1] = v[1];
        tile[r][tx * 4 + 2] = v[2];
        tile[r][tx * 4 + 3] = v[3];
    }
    __syncthreads();
    #pragma unroll
    for (int i = 0; i < 4; ++i) {
        int oc = ty + i * 16;
        half4 v;
        v[0] = tile[tx * 4 + 0][oc];
        v[1] = tile[tx * 4 + 1][oc];
        v[2] = tile[tx * 4 + 2][oc];
        v[3] = tile[tx * 4 + 3][oc];
        *reinterpret_cast<half4*>(&out[(size_t)(c0 + oc) * Cout + r0 + tx * 4]) = v;
    }
}

// Vectorized RoPE: thread = (row bl, 4-h group hq, head slot ns); handles
// NHEADS/NSLOT heads, reusing trig. exp2f timescale + fast __sinf/__cosf
// (args < 256 revolutions; error << fp16 quantum). half4 loads/stores.
template <int NHEADS, int NSLOT, int RS>
__device__ __forceinline__ void rope_fast(_Float16* __restrict__ x,
                                          const int* __restrict__ pos, int vb) {
    const int t = vb * 256 + (int)threadIdx.x;
    const int hq = t & 15;
    const int ns = (t >> 4) % NSLOT;
    const int bl = (t >> 4) / NSLOT;
    const float p = (float)pos[bl];
    const float C = -0.2076205059304601f;   // -log2(10000)/64
    float s[4], c[4];
    #pragma unroll
    for (int j = 0; j < 4; ++j) {
        float ang = p * exp2f((float)(hq * 4 + j) * C);
        s[j] = __sinf(ang);
        c[j] = __cosf(ang);
    }
    #pragma unroll
    for (int i = 0; i < NHEADS / NSLOT; ++i) {
        const int n = ns + i * NSLOT;
        size_t base = (size_t)bl * RS + (size_t)n * HD + hq * 4;
        half4 a  = *reinterpret_cast<half4*>(&x[base]);
        half4 b2 = *reinterpret_cast<half4*>(&x[base + 64]);
        half4 o1, o2;
        #pragma unroll
        for (int j = 0; j < 4; ++j) {
            float x1 = (float)a[j], x2 = (float)b2[j];
            o1[j] = (_Float16)(x1 * c[j] - x2 * s[j]);
            o2[j] = (_Float16)(x2 * c[j] + x1 * s[j]);
        }
        *reinterpret_cast<half4*>(&x[base])      = o1;
        *reinterpret_cast<half4*>(&x[base + 64]) = o2;
    }
}

// prep1: convert Xq, Xkv; transpose Wq, Wk, Wv.  5632 blocks.
__global__ __launch_bounds__(256) void prep1(const float* __restrict__ Xq, _Float16* __restrict__ Xq16,
                                             const float* __restrict__ Xkv, _Float16* __restrict__ Xkv16,
                                             const float* __restrict__ Wq, _Float16* __restrict__ WqT,
                                             const float* __restrict__ Wk, const float* __restrict__ Wv,
                                             _Float16* __restrict__ WkvT) {
    __shared__ _Float16 tile[64][72];
    int bx = blockIdx.x;
    if (bx < 2048) { conv_blk(Xq, Xq16, bx); return; }
    bx -= 2048;
    if (bx < 2048) { conv_blk(Xkv, Xkv16, bx); return; }
    bx -= 2048;
    if (bx < 1024) { tr_blk(Wq, WqT, 2048, 2048, bx & 31, bx >> 5, tile); return; }
    bx -= 1024;
    if (bx < 256) { tr_blk(Wk, WkvT, 2048, 512, bx & 7, bx >> 3, tile); return; }
    bx -= 256;
    tr_blk(Wv, WkvT + (size_t)512 * 2048, 2048, 512, bx & 7, bx >> 3, tile);
}

// prep2: transpose Wo; RoPE on Q and KV (vectorized); V^T.  2048 blocks.
// VTh layout: [(b*NKV+kn)][h(128)][s(1024)] fp16 (V^T per kv-head).
__global__ __launch_bounds__(256) void prep2(const float* __restrict__ Wo, _Float16* __restrict__ WoT,
                                             _Float16* __restrict__ Qh, const int* __restrict__ qpos,
                                             _Float16* __restrict__ KVh, const int* __restrict__ kpos,
                                             _Float16* __restrict__ VTh) {
    __shared__ _Float16 tile[64][72];
    int bx = blockIdx.x;
    if (bx < 1024) { tr_blk(Wo, WoT, 2048, 2048, bx & 31, bx >> 5, tile); return; }
    bx -= 1024;
    if (bx < 512) { rope_fast<NQ, 4, NQ * HD>(Qh, qpos, bx); return; }
    bx -= 512;
    if (bx < 256) { rope_fast<NKV, 2, 1024>(KVh, kpos, bx); return; }
    bx -= 256;
    // V transpose: 256 blocks = 8 heads x 32 tiles (16 s-tiles x 2 h-tiles)
    {
        const int head = bx >> 5;            // b*4 + kn
        const int t = bx & 31;
        const int sx = t & 15, hx = t >> 4;
        const int b = head >> 2, kn = head & 3;
        const _Float16* in = KVh + (size_t)(b * S_SZ) * 1024 + 512 + kn * HD;
        _Float16* out = VTh + (size_t)head * HD * S_SZ;
        tr16_blk(in, out, 1024, 1024, sx * 64, hx * 64, tile);
    }
}

// ---------------------------------------------------------------------------
// GEMM tile body: C[bm:+BM][bn:+BN] = A[.][kbeg:kend] * Bt[.][kbeg:kend]^T
// A,Bt fp16 row-major, row stride K. 4 waves, wave grid 2x2. BK=64.
// Coalesced swizzled staging + 2-phase double-buffer (see round-2 notes).
// ---------------------------------------------------------------------------
template <int BM, int BN, typename TC>
__device__ __forceinline__ void gemm_tile(const _Float16* __restrict__ A,
                                          const _Float16* __restrict__ Bt,
                                          TC* __restrict__ C,
                                          int N, int K, int kbeg, int kend,
                                          int bm, int bn, _Float16* lds) {
    constexpr int ASEG = BM / 8, BSEG = BN / 8, TSEG = ASEG + BSEG, PSEG = TSEG / 4;
    constexpr int BUFSZ = TSEG * 512;           // fp16 elems per LDS buffer
    const int tid = threadIdx.x, lane = tid & 63, w = tid >> 6;
    const int quad = lane >> 4, l16 = lane & 15;
    constexpr int WM = BM / 2, WN = BN / 2, MI = WM / 16, NI = WN / 16;
    const int wm = (w >> 1) * WM, wn = (w & 1) * WN;

    // staging lane geometry: 8 rows x 8 swizzled 16B k-chunks per segment
    const int srl = lane >> 3;              // row within the 8-row stripe
    const int skb = (lane & 7) ^ srl;       // pre-swizzled global k-chunk

    const _Float16* gp[PSEG];
    _Float16* lp[PSEG];
    #pragma unroll
    for (int p = 0; p < PSEG; ++p) {
        int s = w + p * 4;
        if (s < ASEG) {
            gp[p] = A + (size_t)(bm + s * 8 + srl) * K + kbeg + skb * 8;
        } else {
            gp[p] = Bt + (size_t)(bn + (s - ASEG) * 8 + srl) * K + kbeg + skb * 8;
        }
        lp[p] = lds + s * 512;
    }

    f32x4 acc[MI][NI];
    #pragma unroll
    for (int i = 0; i < MI; ++i)
        #pragma unroll
        for (int j = 0; j < NI; ++j)
            acc[i][j] = (f32x4){0.f, 0.f, 0.f, 0.f};

    const int nsteps = (kend - kbeg) >> 6;

    // prologue: stage k-step 0 into buffer 0
    #pragma unroll
    for (int p = 0; p < PSEG; ++p)
        stage16(gp[p], lp[p], lane);
    __syncthreads();                         // vmcnt(0) drain + barrier

    const int rxa = l16 & 7;                 // row&7 for fragment swizzle
    int cur = 0;
    for (int it = 0; it < nsteps; ++it) {
        // issue prefetch of k-step it+1 into the other buffer FIRST
        if (it + 1 < nsteps) {
            const int ko = (it + 1) * 64;
            const int nb = (cur ^ 1) * BUFSZ;
            #pragma unroll
            for (int p = 0; p < PSEG; ++p)
                stage16(gp[p] + ko, lp[p] + nb, lane);
        }
        const _Float16* lb = lds + cur * BUFSZ;
        #pragma unroll
        for (int h = 0; h < 2; ++h) {        // two 32-k MFMA steps per round
            const int kb0 = h * 4 + quad;    // k-chunk this lane needs
            const int kswz = (kb0 ^ rxa) * 8;
            half8 af[MI], bf[NI];
            #pragma unroll
            for (int i = 0; i < MI; ++i) {
                const int r = wm + 16 * i + l16;
                af[i] = *reinterpret_cast<const half8*>(&lb[r * 64 + kswz]);
            }
            #pragma unroll
            for (int j = 0; j < NI; ++j) {
                const int r = wn + 16 * j + l16;
                bf[j] = *reinterpret_cast<const half8*>(&lb[BM * 64 + r * 64 + kswz]);
            }
            #pragma unroll
            for (int i = 0; i < MI; ++i)
                #pragma unroll
                for (int j = 0; j < NI; ++j)
                    acc[i][j] = __builtin_amdgcn_mfma_f32_16x16x32_f16(af[i], bf[j], acc[i][j], 0, 0, 0);
        }
        __syncthreads();   // drains prefetch vmcnt(0); all reads of cur done
        cur ^= 1;
    }

    #pragma unroll
    for (int i = 0; i < MI; ++i)
        #pragma unroll
        for (int j = 0; j < NI; ++j)
            #pragma unroll
            for (int r = 0; r < 4; ++r) {
                size_t idx = (size_t)(bm + wm + 16 * i + quad * 4 + r) * N + bn + wn + 16 * j + l16;
                C[idx] = (TC)acc[i][j][r];
            }
}

// Fused Q-proj + KV-proj: blocks [0,512) -> Q (N=2048); [512,768) -> KV (N=1024).
__global__ __launch_bounds__(256) void proj_fused(const _Float16* __restrict__ Xq,
                                                  const _Float16* __restrict__ WqT,
                                                  _Float16* __restrict__ Qh,
                                                  const _Float16* __restrict__ Xkv,
                                                  const _Float16* __restrict__ WkvT,
                                                  _Float16* __restrict__ KVh) {
    __shared__ __align__(16) _Float16 lds[2 * (128 + 64) * 64];
    int bx = blockIdx.x;
    if (bx < 512) {
        gemm_tile<128, 64, _Float16>(Xq, WqT, Qh, 2048, 2048, 0, 2048,
                                     (bx & 15) * 128, (bx >> 4) * 64, lds);
    } else {
        bx -= 512;
        gemm_tile<128, 64, _Float16>(Xkv, WkvT, KVh, 1024, 2048, 0, 2048,
                                     (bx & 15) * 128, (bx >> 4) * 64, lds);
    }
}

// Out-proj: full K=2048, direct fp32 store (no atomics, no memset). 512 blocks.
__global__ __launch_bounds__(256) void gemm_out(const _Float16* __restrict__ A,
                                                const _Float16* __restrict__ Bt,
                                                float* __restrict__ C) {
    __shared__ __align__(16) _Float16 lds[2 * (128 + 64) * 64];
    const int bx = blockIdx.x;
    gemm_tile<128, 64, float>(A, Bt, C, 2048, 2048, 0, 2048,
                              (bx & 15) * 128, (bx >> 4) * 64, lds);
}

// ---------------------------------------------------------------------------
// Flash attention (non-causal, scale=1.0, GQA group=4), all fp16, fp32 acc.
// Q:(B,T,NQ,HD); KV:(B,S,1024) with K at kn*HD (RoPE'd);
// VTh: per-head V^T [(b*4+kn)][h=128][s=1024]. O:(B,T,NQ,HD).
// Block = 256 thr (4 waves), 64 q-rows of one (b, q-head) -> 512 blocks.
// Round-8 structure (known-best) + DPP reductions (round-9-validated).
//
// XCD-aware remap: the 512 logical blocks form exactly 8 KV-sharing groups
// (b,kn) of 64 consecutive ids; logi = (hw&7)*64 + (hw>>3) pins each group
// to one XCD (hw%8), so its ~1.5 MB working set stays in that XCD's L2.
//
// Staging: async global_load_lds, double-buffered, both-sides XOR chunk
// swizzle; each segment = 64 lanes x 16 B = 512 fp16 (LDS base s*512).
// Softmax: defer-max THR=8 + DPP max16/sum16 (VALU, no ds_bpermute).
// ---------------------------------------------------------------------------
__global__ __launch_bounds__(256) void attn_kernel(const _Float16* __restrict__ Q,
                                                   const _Float16* __restrict__ KV,
                                                   const _Float16* __restrict__ VT,
                                                   _Float16* __restrict__ O) {
    constexpr int KBUF = 64 * 128;            // fp16 per K buffer
    constexpr int VBUF = 128 * 64;            // fp16 per Vt buffer
    constexpr int BUFSZ = KBUF + VBUF;        // 16384 fp16 = 32 KB
    __shared__ __align__(16) _Float16 lds[2 * BUFSZ];       // 64 KB
    __shared__ __align__(16) _Float16 Ps[4][16][72];        // 9 KB
    const int tid = threadIdx.x, lane = tid & 63, w = tid >> 6;
    const int quad = lane >> 4, l16 = lane & 15;
    const int hw = blockIdx.x;
    const int blk = (hw & 7) * 64 + (hw >> 3);   // XCD-aligned logical id
    const int t0 = (blk & 15) * 64;
    const int n  = (blk >> 4) & 15;
    const int b  = blk >> 8;
    const int kn = n >> 2;
    const _Float16* KVb  = KV + (size_t)b * S_SZ * 1024 + kn * HD;
    const _Float16* Vhead = VT + (size_t)(b * NKV + kn) * HD * S_SZ;

    // staging lane geometry (wave-uniform LDS bases; per-lane global addrs)
    const int krow_i = lane >> 4;             // row-in-seg for K (4 rows/seg)
    const int kcp    = lane & 15;             // chunk pos for K
    const int vrow_i = lane >> 3;             // row-in-seg for Vt (8 rows/seg)
    const int vcp    = lane & 7;              // chunk pos for Vt

    half8 qf[4];
    #pragma unroll
    for (int kh = 0; kh < 4; ++kh)
        qf[kh] = load8_f16(&Q[(((size_t)b * T_SZ + t0 + w * 16 + l16) * NQ + n) * HD + kh * 32 + quad * 8]);

    f32x4 o_acc[8];
    #pragma unroll
    for (int i = 0; i < 8; ++i) o_acc[i] = (f32x4){0.f, 0.f, 0.f, 0.f};
    float m_row[4] = {-1e30f, -1e30f, -1e30f, -1e30f};
    float l_part[4] = {0.f, 0.f, 0.f, 0.f};

    // ---- stage one s-tile (64 kv rows) into buffer `buf` -----------------
    auto stage_tile = [&](int s0, int buf) {
        _Float16* kb = lds + buf * BUFSZ;
        _Float16* vb = kb + KBUF;
        #pragma unroll
        for (int j = 0; j < 4; ++j) {
            const int s = w + j * 4;               // segment 0..15
            const int row = 4 * s + krow_i;        // K row 0..63
            const int kc = kcp ^ (row & 7);        // pre-swizzled chunk
            stage16(KVb + (size_t)(s0 + row) * 1024 + kc * 8, kb + s * 512, lane);
        }
        #pragma unroll
        for (int j = 0; j < 4; ++j) {
            const int s = w + j * 4;
            const int row = 8 * s + vrow_i;        // Vt row (h) 0..127
            const int vc = vcp ^ (row & 7);
            stage16(Vhead + (size_t)row * S_SZ + s0 + vc * 8, vb + s * 512, lane);
        }
    };

    stage_tile(0, 0);
    __syncthreads();

    const int rx = l16 & 7;                        // row&7 for all reads
    int cur = 0;
    for (int t = 0; t < S_SZ / 64; ++t) {
        if (t + 1 < S_SZ / 64)
            stage_tile((t + 1) * 64, cur ^ 1);
        const _Float16* Kb = lds + cur * BUFSZ;
        const _Float16* Vb = Kb + KBUF;

        f32x4 sf[4];
        __builtin_amdgcn_s_setprio(1);
        #pragma unroll
        for (int i4 = 0; i4 < 4; ++i4) {
            const int srow = i4 * 16 + l16;        // K row 0..63
            f32x4 sa = (f32x4){0.f, 0.f, 0.f, 0.f};
            #pragma unroll
            for (int kh = 0; kh < 4; ++kh) {
                const int c = kh * 4 + quad;       // chunk 0..15
                half8 bk = *reinterpret_cast<const half8*>(
                    &Kb[srow * 128 + ((c ^ rx) * 8)]);
                sa = __builtin_amdgcn_mfma_f32_16x16x32_f16(qf[kh], bk, sa, 0, 0, 0);
            }
            sf[i4] = sa;
        }
        __builtin_amdgcn_s_setprio(0);

        float mc[4];
        #pragma unroll
        for (int r = 0; r < 4; ++r)
            mc[r] = max16(fmaxf(fmaxf(sf[0][r], sf[1][r]), fmaxf(sf[2][r], sf[3][r])));
        // defer-max: rescale only when a row max grows by more than THR=8.
        bool grow = (mc[0] > m_row[0] + 8.f) | (mc[1] > m_row[1] + 8.f) |
                    (mc[2] > m_row[2] + 8.f) | (mc[3] > m_row[3] + 8.f);
        if (__any(grow)) {
            #pragma unroll
            for (int r = 0; r < 4; ++r) {
                float mn = fmaxf(m_row[r], mc[r]);
                float alpha = __expf(m_row[r] - mn);
                m_row[r] = mn;
                l_part[r] *= alpha;
                #pragma unroll
                for (int ht = 0; ht < 8; ++ht)
                    o_acc[ht][r] *= alpha;
            }
        }
        #pragma unroll
        for (int r = 0; r < 4; ++r) {
            float p0 = __expf(sf[0][r] - m_row[r]);
            float p1 = __expf(sf[1][r] - m_row[r]);
            float p2 = __expf(sf[2][r] - m_row[r]);
            float p3 = __expf(sf[3][r] - m_row[r]);
            l_part[r] += (p0 + p1) + (p2 + p3);
            Ps[w][quad * 4 + r][l16]      = (_Float16)p0;
            Ps[w][quad * 4 + r][16 + l16] = (_Float16)p1;
            Ps[w][quad * 4 + r][32 + l16] = (_Float16)p2;
            Ps[w][quad * 4 + r][48 + l16] = (_Float16)p3;
        }
        __builtin_amdgcn_wave_barrier();
        half8 ap0 = *reinterpret_cast<const half8*>(&Ps[w][l16][quad * 8]);
        half8 ap1 = *reinterpret_cast<const half8*>(&Ps[w][l16][32 + quad * 8]);
        __builtin_amdgcn_wave_barrier();
        __builtin_amdgcn_s_setprio(1);
        #pragma unroll
        for (int ht = 0; ht < 8; ++ht) {
            const int vrow = ht * 16 + l16;        // h row 0..127
            half8 bv0 = *reinterpret_cast<const half8*>(
                &Vb[vrow * 64 + ((quad ^ rx) * 8)]);
            o_acc[ht] = __builtin_amdgcn_mfma_f32_16x16x32_f16(ap0, bv0, o_acc[ht], 0, 0, 0);
            half8 bv1 = *reinterpret_cast<const half8*>(
                &Vb[vrow * 64 + (((4 + quad) ^ rx) * 8)]);
            o_acc[ht] = __builtin_amdgcn_mfma_f32_16x16x32_f16(ap1, bv1, o_acc[ht], 0, 0, 0);
        }
        __builtin_amdgcn_s_setprio(0);

        __syncthreads();     // drains prefetch vmcnt(0); all reads of cur done
        cur ^= 1;
    }

    float inv_l[4];
    #pragma unroll
    for (int r = 0; r < 4; ++r)
        inv_l[r] = 1.f / fmaxf(sum16(l_part[r]), 1e-30f);
    #pragma unroll
    for (int ht = 0; ht < 8; ++ht)
        #pragma unroll
        for (int r = 0; r < 4; ++r)
            O[(((size_t)b * T_SZ + t0 + w * 16 + quad * 4 + r) * NQ + n) * HD + ht * 16 + l16] =
                (_Float16)(o_acc[ht][r] * inv_l[r]);
}

// ---------------------------------------------------------------------------
extern "C" void kernel_launch(void* const* d_in, const int* in_sizes, int n_in,
                              void* d_out, int out_size, void* d_ws, size_t ws_size,
                              hipStream_t stream) {
    const float* Xq   = (const float*)d_in[0];
    const float* Xkv  = (const float*)d_in[1];
    const int*   qpos = (const int*)d_in[2];
    const int*   kpos = (const int*)d_in[3];
    const float* Wq   = (const float*)d_in[4];
    const float* Wk   = (const float*)d_in[5];
    const float* Wv   = (const float*)d_in[6];
    const float* Wo   = (const float*)d_in[7];
    float* out = (float*)d_out;

    // workspace packing with lifetime reuse
    const size_t SZ8 = 8388608;
    uint8_t* ws = (uint8_t*)d_ws;
    _Float16* Xq16  = (_Float16*)(ws);
    _Float16* Xkv16 = (_Float16*)(ws + SZ8);
    _Float16* WqT   = (_Float16*)(ws + 2 * SZ8);
    _Float16* WkvT  = (_Float16*)(ws + 3 * SZ8);
    _Float16* Qh    = (_Float16*)(ws + 3 * SZ8 + 4194304);
    _Float16* Ah  = Xq16;   // attn out reuses Xq16 (dead after proj)
    _Float16* WoT = Xkv16;  // WoT reuses Xkv16 (dead after proj)
    _Float16* KVh = WqT;    // KV reuses WqT (dead after proj)
    _Float16* VTh = WkvT;   // V^T reuses WkvT (dead after proj), 2 MB of 4 MB

    dim3 blk(256);
    // prep1: converts + Wq/Wk/Wv transposes (one launch)
    prep1<<<5632, blk, 0, stream>>>(Xq, Xq16, Xkv, Xkv16, Wq, WqT, Wk, Wv, WkvT);
    // fused Q + KV projection (768 blocks, coalesced swizzled staging)
    proj_fused<<<768, blk, 0, stream>>>(Xq16, WqT, Qh, Xkv16, WkvT, KVh);
    // prep2: Wo transpose + vectorized RoPE + V^T (2048 blocks)
    prep2<<<2048, blk, 0, stream>>>(Wo, WoT, Qh, qpos, KVh, kpos, VTh);
    // GQA flash attention (512 blocks x 256 thr, XCD-aligned, async dbuf)
    attn_kernel<<<512, blk, 0, stream>>>(Qh, KVh, VTh, Ah);
    // output projection: full-K, direct fp32 store (512 blocks)
    gemm_out<<<512, blk, 0, stream>>>(Ah, WoT, out);
}